// Round 1
// baseline (12350.560 us; speedup 1.0000x reference)
//
#include <hip/hip_runtime.h>

#define VOCAB 100000
#define E 300
#define H 300
#define T 128
#define BB 128
#define NT 255   // 2T-1
#define PAD 1
#define NOUT 5

// scan configuration
#define RG 8        // row groups (16 rows each)
#define RPB 16      // rows per block
#define CB 30       // col blocks (10 h-dims each)
#define DPB 10      // h dims per block
#define COLS 50     // gate cols per block (5*DPB)
#define KP 608      // padded K (600 -> 608, /8 and /4 friendly)
#define KC 8        // k chunks per column
#define KT 76       // k per chunk (608/8)
#define K4N 19      // float4 iterations per chunk (76/4)
#define SCAN_THREADS 448
#define MV_THREADS 400   // 50 cols * 8 kc
#define CU_THREADS 160   // 16 rows * 10 dims

__device__ __forceinline__ float sigmoidf_(float x) { return 1.0f / (1.0f + expf(-x)); }

// ---------------------------------------------------------------------------
// Prep: transpose W_reduce to col-major, reorder cols by (cb, gate, jj), pad K.
// Wt[col'][k], col' = cb*50 + g*10 + jj  <->  orig col j = g*300 + cb*10 + jj
// ---------------------------------------------------------------------------
__global__ void prep_kernel(const float* __restrict__ Wr, const float* __restrict__ br,
                            float* __restrict__ Wt, float* __restrict__ bpr) {
    int idx = blockIdx.x * 256 + threadIdx.x;
    int total = 1500 * KP;
    if (idx < total) {
        int col = idx / KP, k = idx % KP;
        int cb = col / COLS, rr = col % COLS;
        int g = rr / DPB, jj = rr % DPB;
        int jo = g * 300 + cb * DPB + jj;
        Wt[idx] = (k < 600) ? Wr[k * 1500 + jo] : 0.0f;
        if (k == 0) bpr[col] = br[jo];
    }
}

// ---------------------------------------------------------------------------
// Schedule: per-row stack-machine replay. Emits per (step,row):
//   ltag/rtag: -1 = zeros, [0,128) = leaf index, >=1000 = reduce rid+1000
//   dtag: dest rid (or -1 if this row doesn't reduce at this step)
// ---------------------------------------------------------------------------
__global__ void sched_kernel(const int* __restrict__ trans,
                             int* __restrict__ sl, int* __restrict__ sr, int* __restrict__ sd,
                             int* __restrict__ root_tag) {
    __shared__ int stk[64][BB];          // depth-major: lanes hit distinct banks
    int row = threadIdx.x;               // 128 threads
    for (int d = 0; d < 64; ++d) stk[d][row] = -1;
    int sp = 0, bp = T - 1, rid = 0;
    for (int t = 0; t < NT; ++t) {
        int tr = trans[t * BB + row];
        int lt = -1, rt = -1, ds = -1;
        if (tr == 0) {                   // shift
            int leaf = bp > 0 ? bp : 0;
            if (sp >= 0 && sp < 64) stk[sp][row] = leaf;
            sp += 1; bp -= 1;
        } else {                         // reduce
            int ip = sp - 2 > 0 ? sp - 2 : 0; if (ip > 63) ip = 63;
            int rp = sp - 1 > 0 ? sp - 1 : 0; if (rp > 63) rp = 63;
            lt = stk[ip][row];
            rt = stk[rp][row];
            ds = rid;
            stk[ip][row] = 1000 + rid;
            rid += 1; sp -= 1;
        }
        sl[t * BB + row] = lt; sr[t * BB + row] = rt; sd[t * BB + row] = ds;
    }
    int rp = sp - 1 > 0 ? sp - 1 : 0; if (rp > 63) rp = 63;
    root_tag[row] = stk[rp][row];
}

// ---------------------------------------------------------------------------
// Events: list of steps where any row reduces (these are the sync events).
// ---------------------------------------------------------------------------
__global__ void events_kernel(const int* __restrict__ trans,
                              int* __restrict__ ev_t, int* __restrict__ ne) {
    __shared__ int anyf[NT];
    int t = threadIdx.x;                 // 256 threads
    if (t < NT) {
        const int4* p = (const int4*)(trans + t * BB);
        int o = 0;
        for (int i = 0; i < BB / 4; ++i) { int4 v = p[i]; o |= v.x | v.y | v.z | v.w; }
        anyf[t] = (o != 0) ? 1 : 0;
    }
    __syncthreads();
    if (t == 0) {
        int n = 0;
        for (int i = 0; i < NT; ++i) if (anyf[i]) ev_t[n++] = i;
        *ne = n;
    }
}

// ---------------------------------------------------------------------------
// Prologue: h_buf/c_buf = fused embed-gather + two GEMMs + activations. f32.
// Block: 32 token-rows staged in LDS, 320 threads (thread = output col n).
// ---------------------------------------------------------------------------
__global__ __launch_bounds__(320) void prologue_kernel(
    const int* __restrict__ tokens, const float* __restrict__ embed,
    const float* __restrict__ Wp, const float* __restrict__ bp_,
    const float* __restrict__ Wg, const float* __restrict__ bg_,
    float* __restrict__ hbuf, float* __restrict__ cbuf) {
    __shared__ float As[32][300];
    int m0 = blockIdx.x * 32;
    int tid = threadIdx.x;
    for (int idx = tid; idx < 32 * 300; idx += 320) {
        int r = idx / 300, c = idx % 300;
        int tok = tokens[m0 + r];
        As[r][c] = (tok == PAD) ? 0.0f : embed[(size_t)tok * 300 + c];
    }
    __syncthreads();
    int n = tid;
    if (n < 300) {
        float accP[32], accG[32];
        #pragma unroll
        for (int m = 0; m < 32; ++m) { accP[m] = 0.f; accG[m] = 0.f; }
        for (int k = 0; k < 300; ++k) {
            float wp = Wp[k * 300 + n], wg = Wg[k * 300 + n];
            #pragma unroll
            for (int m = 0; m < 32; ++m) {
                float a = As[m][k];
                accP[m] += a * wp;
                accG[m] += a * wg;
            }
        }
        float bpv = bp_[n], bgv = bg_[n];
        for (int m = 0; m < 32; ++m) {
            float c = accP[m] + bpv;
            float g = accG[m] + bgv;
            float h = tanhf(c) * sigmoidf_(g);
            hbuf[(size_t)(m0 + m) * 300 + n] = h;
            cbuf[(size_t)(m0 + m) * 300 + n] = c;
        }
    }
}

// ---------------------------------------------------------------------------
// Scan: persistent kernel, 240 blocks = 8 row-groups x 30 col-blocks.
// Sync = per-row-group done-counters (release/acquire, agent scope).
// ---------------------------------------------------------------------------
struct ScanArgs {
    const int* sl; const int* sr; const int* sd;
    const int* ev_t; const int* ne;
    const float* hbuf; const float* cbuf;
    float* res_h; float* res_c;
    const float* Wt; const float* bpr;
    int* done;
};

__global__ __launch_bounds__(SCAN_THREADS) void scan_kernel(ScanArgs a) {
    __shared__ __align__(16) float xs[RPB][KP];   // 38.9 KB staged [h_l | h_r | pad]
    __shared__ float sums[COLS][RPB];             // gate logits slice
    __shared__ int ltg[RPB], rtg[RPB], dtg[RPB];
    const int tid = threadIdx.x;
    const int bid = blockIdx.x;
    const int rg = bid / CB;
    const int cb = bid % CB;
    const int row0 = rg * RPB;
    const int NEv = *a.ne;

    for (int e = 0; e < NEv; ++e) {
        if (e > 0) {
            while (__hip_atomic_load(&a.done[rg * 256 + (e - 1)],
                                     __ATOMIC_ACQUIRE, __HIP_MEMORY_SCOPE_AGENT) < CB)
                __builtin_amdgcn_s_sleep(1);
        }
        __syncthreads();
        int t = a.ev_t[e];
        if (tid < RPB) {
            ltg[tid] = a.sl[t * BB + row0 + tid];
            rtg[tid] = a.sr[t * BB + row0 + tid];
            dtg[tid] = a.sd[t * BB + row0 + tid];
        }
        __syncthreads();

        // stage x = [h_left | h_right | 0 pad] per row (zeros for idle rows)
        {
            int r = tid / KP, k = tid % KP;       // stride 448 < 608: wrap at most once
            for (int idx = tid; idx < RPB * KP; idx += SCAN_THREADS) {
                float v = 0.0f;
                if (k < 600) {
                    int tag = (k < 300) ? ltg[r] : rtg[r];
                    int kk = (k < 300) ? k : (k - 300);
                    if (tag >= 0) {
                        const float* src = (tag < 1000)
                            ? (a.hbuf + ((size_t)(row0 + r) * T + tag) * H)
                            : (a.res_h + ((size_t)(row0 + r) * 32 + ((tag - 1000) & 31)) * H);
                        v = src[kk];
                    }
                }
                xs[r][k] = v;
                k += SCAN_THREADS;
                if (k >= KP) { k -= KP; r += 1; }
            }
        }
        __syncthreads();

        // matvec: thread = (col j, k-chunk kc); acc over 16 rows; kc-reduce via shfl
        if (tid < MV_THREADS) {
            int j = tid >> 3;
            int kc = tid & 7;
            int col = cb * COLS + j;
            const float* wbase = a.Wt + (size_t)col * KP + kc * KT;
            float acc[RPB];
            #pragma unroll
            for (int r = 0; r < RPB; ++r) acc[r] = 0.f;
            #pragma unroll 1
            for (int k4 = 0; k4 < K4N; ++k4) {
                float4 w = *(const float4*)(wbase + k4 * 4);
                #pragma unroll
                for (int r = 0; r < RPB; ++r) {
                    float4 xv = *(const float4*)(&xs[r][kc * KT + k4 * 4]);
                    acc[r] += w.x * xv.x + w.y * xv.y + w.z * xv.z + w.w * xv.w;
                }
            }
            #pragma unroll
            for (int d = 1; d < 8; d <<= 1) {
                #pragma unroll
                for (int r = 0; r < RPB; ++r) acc[r] += __shfl_xor(acc[r], d, 64);
            }
            if (kc == 0) {
                float bb = a.bpr[col];
                #pragma unroll
                for (int r = 0; r < RPB; ++r) sums[j][r] = acc[r] + bb;
            }
        }
        __syncthreads();

        // cell update for this block's 10 h-dims x 16 rows
        if (tid < CU_THREADS) {
            int r = tid & 15, jj = tid >> 4;
            int ds = dtg[r];
            if (ds >= 0) {
                int dim = cb * DPB + jj;
                float iv = sums[jj][r];
                float fl = sums[DPB + jj][r];
                float fr = sums[2 * DPB + jj][r];
                float gv = sums[3 * DPB + jj][r];
                float ov = sums[4 * DPB + jj][r];
                int lt = ltg[r], rt = rtg[r];
                float cl = 0.f, cr = 0.f;
                if (lt >= 0) cl = (lt < 1000)
                    ? a.cbuf[((size_t)(row0 + r) * T + lt) * H + dim]
                    : a.res_c[((size_t)(row0 + r) * 32 + ((lt - 1000) & 31)) * H + dim];
                if (rt >= 0) cr = (rt < 1000)
                    ? a.cbuf[((size_t)(row0 + r) * T + rt) * H + dim]
                    : a.res_c[((size_t)(row0 + r) * 32 + ((rt - 1000) & 31)) * H + dim];
                float c = sigmoidf_(iv) * tanhf(gv) + sigmoidf_(fl) * cl + sigmoidf_(fr) * cr;
                float h = sigmoidf_(ov) * tanhf(c);
                size_t ro = ((size_t)(row0 + r) * 32 + (ds & 31)) * H + dim;
                a.res_h[ro] = h;
                a.res_c[ro] = c;
            }
        }
        __threadfence();       // each thread drains its own global writes to agent scope
        __syncthreads();
        if (tid == 0)
            __hip_atomic_fetch_add(&a.done[rg * 256 + e], 1,
                                   __ATOMIC_RELEASE, __HIP_MEMORY_SCOPE_AGENT);
    }
}

// ---------------------------------------------------------------------------
// Epilogue: out = root_h @ W_out + b_out
// ---------------------------------------------------------------------------
__global__ void epilogue_kernel(const int* __restrict__ root_tag,
                                const float* __restrict__ hbuf, const float* __restrict__ res_h,
                                const float* __restrict__ Wo, const float* __restrict__ bo,
                                float* __restrict__ out) {
    int row = blockIdx.x;
    int lane = threadIdx.x;  // 64
    int tag = root_tag[row];
    const float* h = nullptr;
    if (tag >= 0)
        h = (tag < 1000) ? hbuf + ((size_t)row * T + tag) * H
                         : res_h + ((size_t)row * 32 + ((tag - 1000) & 31)) * H;
    float acc[NOUT] = {0, 0, 0, 0, 0};
    for (int k = lane; k < H; k += 64) {
        float hv = h ? h[k] : 0.f;
        #pragma unroll
        for (int g = 0; g < NOUT; ++g) acc[g] += hv * Wo[k * NOUT + g];
    }
    #pragma unroll
    for (int d = 1; d < 64; d <<= 1) {
        #pragma unroll
        for (int g = 0; g < NOUT; ++g) acc[g] += __shfl_xor(acc[g], d, 64);
    }
    if (lane == 0) {
        #pragma unroll
        for (int g = 0; g < NOUT; ++g) out[row * NOUT + g] = acc[g] + bo[g];
    }
}

// ---------------------------------------------------------------------------
extern "C" void kernel_launch(void* const* d_in, const int* in_sizes, int n_in,
                              void* d_out, int out_size, void* d_ws, size_t ws_size,
                              hipStream_t stream) {
    const int*   tokens = (const int*)d_in[0];
    const int*   trans  = (const int*)d_in[1];
    const float* embed  = (const float*)d_in[2];
    const float* Wp     = (const float*)d_in[3];
    const float* bp     = (const float*)d_in[4];
    const float* Wg     = (const float*)d_in[5];
    const float* bg     = (const float*)d_in[6];
    const float* Wr     = (const float*)d_in[7];
    const float* br     = (const float*)d_in[8];
    const float* Wo     = (const float*)d_in[9];
    const float* bo     = (const float*)d_in[10];
    float* out = (float*)d_out;

    char* ws = (char*)d_ws;
    size_t o = 0;
    auto alloc = [&](size_t bytes) {
        char* p = ws + o;
        o = (o + bytes + 255) & ~(size_t)255;
        return p;
    };
    float* hbuf  = (float*)alloc((size_t)BB * T * H * 4);     // 19.7 MB
    float* cbuf  = (float*)alloc((size_t)BB * T * H * 4);     // 19.7 MB
    float* res_h = (float*)alloc((size_t)BB * 32 * H * 4);    // 4.9 MB (rid mod 32 slots)
    float* res_c = (float*)alloc((size_t)BB * 32 * H * 4);    // 4.9 MB
    float* Wt    = (float*)alloc((size_t)1500 * KP * 4);      // 3.65 MB
    float* bpr   = (float*)alloc(1500 * 4);
    int* sl      = (int*)alloc((size_t)NT * BB * 4);
    int* sr      = (int*)alloc((size_t)NT * BB * 4);
    int* sd      = (int*)alloc((size_t)NT * BB * 4);
    int* ev_t    = (int*)alloc(256 * 4);
    int* ne      = (int*)alloc(4);
    int* root    = (int*)alloc(BB * 4);
    int* done    = (int*)alloc(RG * 256 * 4);
    (void)ws_size; (void)in_sizes; (void)n_in; (void)out_size;

    hipMemsetAsync(done, 0, RG * 256 * 4, stream);
    prep_kernel<<<(1500 * KP + 255) / 256, 256, 0, stream>>>(Wr, br, Wt, bpr);
    sched_kernel<<<1, BB, 0, stream>>>(trans, sl, sr, sd, root);
    events_kernel<<<1, 256, 0, stream>>>(trans, ev_t, ne);
    prologue_kernel<<<(BB * T) / 32, 320, 0, stream>>>(tokens, embed, Wp, bp, Wg, bg, hbuf, cbuf);

    ScanArgs sa { sl, sr, sd, ev_t, ne, hbuf, cbuf, res_h, res_c, Wt, bpr, done };
    void* args[] = { &sa };
    hipLaunchCooperativeKernel((const void*)scan_kernel, dim3(RG * CB), dim3(SCAN_THREADS),
                               args, 0, stream);

    epilogue_kernel<<<BB, 64, 0, stream>>>(root, hbuf, res_h, Wo, bo, out);
}

// Round 2
// 3921.572 us; speedup vs baseline: 3.1494x; 3.1494x over previous
//
#include <hip/hip_runtime.h>

#define VOCAB 100000
#define E 300
#define H 300
#define T 128
#define BB 128
#define NT 255   // 2T-1
#define PAD 1
#define NOUT 5

// scan configuration
#define RG 8          // row groups (16 rows each)
#define RPB 16        // rows per block
#define CB 30         // col blocks (10 h-dims each)
#define DPB 10        // h dims per block
#define COLS 50       // gate cols per block (5*DPB)
#define KP 608        // padded K (600 -> 608); KT=76 == 12 mod 32 -> 8 distinct bank quads
#define KC 8          // k chunks per column group
#define KT 76         // k per chunk
#define K4N 19        // float4 iterations per chunk
#define SCAN_THREADS 320
#define MV_THREADS 160   // 10 col-groups x 2 row-halves x 8 kc
#define CU_THREADS 160   // 16 rows x 10 dims
#define SLOTS 32

__device__ __forceinline__ float sigmoidf_(float x) { return 1.0f / (1.0f + expf(-x)); }

// ---------------------------------------------------------------------------
// Prep: transpose W_reduce to col-major, reorder cols by (cb, gate, jj), pad K.
// Wt[col'][k], col' = cb*50 + g*10 + jj  <->  orig col j = g*300 + cb*10 + jj
// ---------------------------------------------------------------------------
__global__ void prep_kernel(const float* __restrict__ Wr, const float* __restrict__ br,
                            float* __restrict__ Wt, float* __restrict__ bpr) {
    int idx = blockIdx.x * 256 + threadIdx.x;
    int total = 1500 * KP;
    if (idx < total) {
        int col = idx / KP, k = idx % KP;
        int cb = col / COLS, rr = col % COLS;
        int g = rr / DPB, jj = rr % DPB;
        int jo = g * 300 + cb * DPB + jj;
        Wt[idx] = (k < 600) ? Wr[k * 1500 + jo] : 0.0f;
        if (k == 0) bpr[col] = br[jo];
    }
}

// ---------------------------------------------------------------------------
// Schedule: per-row stack-machine replay (tags: -1 zero, [0,128) leaf, >=1000 rid)
// ---------------------------------------------------------------------------
__global__ void sched_kernel(const int* __restrict__ trans,
                             int* __restrict__ sl, int* __restrict__ sr, int* __restrict__ sd,
                             int* __restrict__ root_tag) {
    __shared__ int stk[64][BB];
    int row = threadIdx.x;               // 128 threads
    for (int d = 0; d < 64; ++d) stk[d][row] = -1;
    int sp = 0, bp = T - 1, rid = 0;
    for (int t = 0; t < NT; ++t) {
        int tr = trans[t * BB + row];
        int lt = -1, rt = -1, ds = -1;
        if (tr == 0) {
            int leaf = bp > 0 ? bp : 0;
            if (sp >= 0 && sp < 64) stk[sp][row] = leaf;
            sp += 1; bp -= 1;
        } else {
            int ip = sp - 2 > 0 ? sp - 2 : 0; if (ip > 63) ip = 63;
            int rp = sp - 1 > 0 ? sp - 1 : 0; if (rp > 63) rp = 63;
            lt = stk[ip][row];
            rt = stk[rp][row];
            ds = rid;
            stk[ip][row] = 1000 + rid;
            rid += 1; sp -= 1;
        }
        sl[t * BB + row] = lt; sr[t * BB + row] = rt; sd[t * BB + row] = ds;
    }
    int rp = sp - 1 > 0 ? sp - 1 : 0; if (rp > 63) rp = 63;
    root_tag[row] = stk[rp][row];
}

// ---------------------------------------------------------------------------
// Events: steps where any row reduces
// ---------------------------------------------------------------------------
__global__ void events_kernel(const int* __restrict__ trans,
                              int* __restrict__ ev_t, int* __restrict__ ne) {
    __shared__ int anyf[NT];
    int t = threadIdx.x;
    if (t < NT) {
        const int4* p = (const int4*)(trans + t * BB);
        int o = 0;
        for (int i = 0; i < BB / 4; ++i) { int4 v = p[i]; o |= v.x | v.y | v.z | v.w; }
        anyf[t] = (o != 0) ? 1 : 0;
    }
    __syncthreads();
    if (t == 0) {
        int n = 0;
        for (int i = 0; i < NT; ++i) if (anyf[i]) ev_t[n++] = i;
        *ne = n;
    }
}

// ---------------------------------------------------------------------------
// Prologue: h_buf/c_buf. float4 LDS broadcast reads -> VALU-bound.
// ---------------------------------------------------------------------------
__global__ __launch_bounds__(320) void prologue_kernel(
    const int* __restrict__ tokens, const float* __restrict__ embed,
    const float* __restrict__ Wp, const float* __restrict__ bp_,
    const float* __restrict__ Wg, const float* __restrict__ bg_,
    float* __restrict__ hbuf, float* __restrict__ cbuf) {
    __shared__ __align__(16) float As[32][304];
    int m0 = blockIdx.x * 32;
    int tid = threadIdx.x;
    for (int idx = tid; idx < 32 * 300; idx += 320) {
        int r = idx / 300, c = idx % 300;
        int tok = tokens[m0 + r];
        As[r][c] = (tok == PAD) ? 0.0f : embed[(size_t)tok * 300 + c];
    }
    __syncthreads();
    int n = tid;
    if (n < 300) {
        float accP[32], accG[32];
        #pragma unroll
        for (int m = 0; m < 32; ++m) { accP[m] = 0.f; accG[m] = 0.f; }
        #pragma unroll 1
        for (int k4 = 0; k4 < 75; ++k4) {
            int k = k4 * 4;
            float wp0 = Wp[(k + 0) * 300 + n], wp1 = Wp[(k + 1) * 300 + n];
            float wp2 = Wp[(k + 2) * 300 + n], wp3 = Wp[(k + 3) * 300 + n];
            float wg0 = Wg[(k + 0) * 300 + n], wg1 = Wg[(k + 1) * 300 + n];
            float wg2 = Wg[(k + 2) * 300 + n], wg3 = Wg[(k + 3) * 300 + n];
            #pragma unroll
            for (int m = 0; m < 32; ++m) {
                float4 av = *(const float4*)(&As[m][k]);
                accP[m] += av.x * wp0 + av.y * wp1 + av.z * wp2 + av.w * wp3;
                accG[m] += av.x * wg0 + av.y * wg1 + av.z * wg2 + av.w * wg3;
            }
        }
        float bpv = bp_[n], bgv = bg_[n];
        #pragma unroll 1
        for (int m = 0; m < 32; ++m) {
            float c = accP[m] + bpv;
            float g = accG[m] + bgv;
            float h = tanhf(c) * sigmoidf_(g);
            hbuf[(size_t)(m0 + m) * 300 + n] = h;
            cbuf[(size_t)(m0 + m) * 300 + n] = c;
        }
    }
}

// ---------------------------------------------------------------------------
// Scan: persistent kernel, 240 blocks = 8 row-groups x 30 col-blocks.
// Cross-block data (res_h, done) goes through the memory-side coherence point
// via RELAXED agent-scope atomics (sc0sc1, NO buffer_inv / buffer_wbl2).
// res_c is block-private (same (rg,cb) writes and reads it) -> plain cached.
// ---------------------------------------------------------------------------
struct ScanArgs {
    const int* sl; const int* sr; const int* sd;
    const int* ev_t; const int* ne;
    const float* hbuf; const float* cbuf;
    float* res_h; float* res_c;
    const float* Wt; const float* bpr;
    int* done;
};

__global__ __launch_bounds__(SCAN_THREADS) void scan_kernel(ScanArgs a) {
    __shared__ __align__(16) float xs[RPB][KP];   // 38.9 KB  [h_l | h_r | pad]
    __shared__ float sums[COLS][17];              // padded: conflict-free cell reads
    __shared__ int ltg[RPB], rtg[RPB], dtg[RPB];
    const int tid = threadIdx.x;
    const int bid = blockIdx.x;
    const int rg = bid / CB;
    const int cb = bid % CB;
    const int row0 = rg * RPB;
    const int NEv = *a.ne;

    for (int e = 0; e < NEv; ++e) {
        int t = a.ev_t[e];
        if (tid < RPB) {
            ltg[tid] = a.sl[t * BB + row0 + tid];
            rtg[tid] = a.sr[t * BB + row0 + tid];
            dtg[tid] = a.sd[t * BB + row0 + tid];
        }
        __syncthreads();

        // ---- phase A: stage everything NOT depending on prev event (leaves, zeros)
        for (int r = 0; r < RPB; ++r) {
            int lt = ltg[r], rt = rtg[r];
            for (int k = tid; k < KP; k += SCAN_THREADS) {
                int tag = (k < 300) ? lt : ((k < 600) ? rt : -1);
                if (tag < 1000) {
                    float v = 0.0f;
                    if (tag >= 0)
                        v = a.hbuf[((size_t)(row0 + r) * T + tag) * H + (k < 300 ? k : k - 300)];
                    xs[r][k] = v;
                }
            }
        }

        // ---- wait for previous event's h to be published (single-thread poll,
        //      relaxed agent load = coherence-point read, no cache invalidates)
        if (e > 0 && tid == 0) {
            int guard = 0;
            while (__hip_atomic_load(&a.done[rg * 256 + (e - 1)],
                                     __ATOMIC_RELAXED, __HIP_MEMORY_SCOPE_AGENT) < CB) {
                __builtin_amdgcn_s_sleep(2);
                if (++guard > (1 << 22)) break;
            }
        }
        __syncthreads();

        // ---- phase B: stage reduce-result operands from res_h (coherence-point loads)
        for (int r = 0; r < RPB; ++r) {
            int lt = ltg[r], rt = rtg[r];
            for (int k = tid; k < 600; k += SCAN_THREADS) {
                int tag = (k < 300) ? lt : rt;
                if (tag >= 1000) {
                    int kk = (k < 300) ? k : (k - 300);
                    const float* src = a.res_h +
                        ((size_t)(row0 + r) * SLOTS + ((tag - 1000) & (SLOTS - 1))) * H + kk;
                    xs[r][k] = __hip_atomic_load((float*)src, __ATOMIC_RELAXED,
                                                 __HIP_MEMORY_SCOPE_AGENT);
                }
            }
        }
        __syncthreads();

        // ---- matvec: thread = (col-group jg of 5, row-half rg8 of 8, k-chunk kc)
        if (tid < MV_THREADS) {
            int kc = tid & 7;
            int rg8 = (tid >> 3) & 1;
            int jg = tid >> 4;                    // 0..9
            int r0 = rg8 * 8;
            const float* wbase = a.Wt + ((size_t)(cb * COLS + jg * 5)) * KP + kc * KT;
            float acc[5][8];
            #pragma unroll
            for (int cc = 0; cc < 5; ++cc)
                #pragma unroll
                for (int rr = 0; rr < 8; ++rr) acc[cc][rr] = 0.f;
            #pragma unroll 2
            for (int k4 = 0; k4 < K4N; ++k4) {
                float4 w0 = *(const float4*)(wbase + 0 * KP + k4 * 4);
                float4 w1 = *(const float4*)(wbase + 1 * KP + k4 * 4);
                float4 w2 = *(const float4*)(wbase + 2 * KP + k4 * 4);
                float4 w3 = *(const float4*)(wbase + 3 * KP + k4 * 4);
                float4 w4 = *(const float4*)(wbase + 4 * KP + k4 * 4);
                #pragma unroll
                for (int rr = 0; rr < 8; ++rr) {
                    float4 xv = *(const float4*)(&xs[r0 + rr][kc * KT + k4 * 4]);
                    acc[0][rr] += w0.x * xv.x + w0.y * xv.y + w0.z * xv.z + w0.w * xv.w;
                    acc[1][rr] += w1.x * xv.x + w1.y * xv.y + w1.z * xv.z + w1.w * xv.w;
                    acc[2][rr] += w2.x * xv.x + w2.y * xv.y + w2.z * xv.z + w2.w * xv.w;
                    acc[3][rr] += w3.x * xv.x + w3.y * xv.y + w3.z * xv.z + w3.w * xv.w;
                    acc[4][rr] += w4.x * xv.x + w4.y * xv.y + w4.z * xv.z + w4.w * xv.w;
                }
            }
            #pragma unroll
            for (int d = 1; d < 8; d <<= 1)
                #pragma unroll
                for (int cc = 0; cc < 5; ++cc)
                    #pragma unroll
                    for (int rr = 0; rr < 8; ++rr)
                        acc[cc][rr] += __shfl_xor(acc[cc][rr], d, 64);
            if (kc == 0) {
                #pragma unroll
                for (int cc = 0; cc < 5; ++cc) {
                    float bb = a.bpr[cb * COLS + jg * 5 + cc];
                    #pragma unroll
                    for (int rr = 0; rr < 8; ++rr)
                        sums[jg * 5 + cc][r0 + rr] = acc[cc][rr] + bb;
                }
            }
        }
        __syncthreads();

        // ---- cell update: 16 rows x 10 dims; res_c block-private (cached),
        //      res_h published via coherence-point stores
        if (tid < CU_THREADS) {
            int r = tid & 15, jj = tid >> 4;
            int ds = dtg[r];
            if (ds >= 0) {
                int dim = cb * DPB + jj;
                float iv = sums[jj][r];
                float fl = sums[DPB + jj][r];
                float fr = sums[2 * DPB + jj][r];
                float gv = sums[3 * DPB + jj][r];
                float ov = sums[4 * DPB + jj][r];
                int lt = ltg[r], rt = rtg[r];
                float cl = 0.f, cr = 0.f;
                if (lt >= 0) cl = (lt < 1000)
                    ? a.cbuf[((size_t)(row0 + r) * T + lt) * H + dim]
                    : a.res_c[((size_t)(row0 + r) * SLOTS + ((lt - 1000) & (SLOTS - 1))) * H + dim];
                if (rt >= 0) cr = (rt < 1000)
                    ? a.cbuf[((size_t)(row0 + r) * T + rt) * H + dim]
                    : a.res_c[((size_t)(row0 + r) * SLOTS + ((rt - 1000) & (SLOTS - 1))) * H + dim];
                float c = sigmoidf_(iv) * tanhf(gv) + sigmoidf_(fl) * cl + sigmoidf_(fr) * cr;
                float h = sigmoidf_(ov) * tanhf(c);
                size_t ro = ((size_t)(row0 + r) * SLOTS + (ds & (SLOTS - 1))) * H + dim;
                a.res_c[ro] = c;                                  // block-private, cached
                __hip_atomic_store(&a.res_h[ro], h, __ATOMIC_RELAXED,
                                   __HIP_MEMORY_SCOPE_AGENT);     // coherence point
            }
        }
        // drain own stores to the coherence point (plain waitcnt, no cache flush)
        asm volatile("s_waitcnt vmcnt(0)" ::: "memory");
        __syncthreads();
        if (tid == 0)
            __hip_atomic_fetch_add(&a.done[rg * 256 + e], 1,
                                   __ATOMIC_RELAXED, __HIP_MEMORY_SCOPE_AGENT);
    }
}

// ---------------------------------------------------------------------------
// Epilogue: out = root_h @ W_out + b_out
// ---------------------------------------------------------------------------
__global__ void epilogue_kernel(const int* __restrict__ root_tag,
                                const float* __restrict__ hbuf, const float* __restrict__ res_h,
                                const float* __restrict__ Wo, const float* __restrict__ bo,
                                float* __restrict__ out) {
    int row = blockIdx.x;
    int lane = threadIdx.x;  // 64
    int tag = root_tag[row];
    const float* h = nullptr;
    if (tag >= 0)
        h = (tag < 1000) ? hbuf + ((size_t)row * T + tag) * H
                         : res_h + ((size_t)row * SLOTS + ((tag - 1000) & (SLOTS - 1))) * H;
    float acc[NOUT] = {0, 0, 0, 0, 0};
    for (int k = lane; k < H; k += 64) {
        float hv = h ? h[k] : 0.f;
        #pragma unroll
        for (int g = 0; g < NOUT; ++g) acc[g] += hv * Wo[k * NOUT + g];
    }
    #pragma unroll
    for (int d = 1; d < 64; d <<= 1) {
        #pragma unroll
        for (int g = 0; g < NOUT; ++g) acc[g] += __shfl_xor(acc[g], d, 64);
    }
    if (lane == 0) {
        #pragma unroll
        for (int g = 0; g < NOUT; ++g) out[row * NOUT + g] = acc[g] + bo[g];
    }
}

// ---------------------------------------------------------------------------
extern "C" void kernel_launch(void* const* d_in, const int* in_sizes, int n_in,
                              void* d_out, int out_size, void* d_ws, size_t ws_size,
                              hipStream_t stream) {
    const int*   tokens = (const int*)d_in[0];
    const int*   trans  = (const int*)d_in[1];
    const float* embed  = (const float*)d_in[2];
    const float* Wp     = (const float*)d_in[3];
    const float* bp     = (const float*)d_in[4];
    const float* Wg     = (const float*)d_in[5];
    const float* bg     = (const float*)d_in[6];
    const float* Wr     = (const float*)d_in[7];
    const float* br     = (const float*)d_in[8];
    const float* Wo     = (const float*)d_in[9];
    const float* bo     = (const float*)d_in[10];
    float* out = (float*)d_out;

    char* ws = (char*)d_ws;
    size_t o = 0;
    auto alloc = [&](size_t bytes) {
        char* p = ws + o;
        o = (o + bytes + 255) & ~(size_t)255;
        return p;
    };
    float* hbuf  = (float*)alloc((size_t)BB * T * H * 4);     // 19.7 MB
    float* cbuf  = (float*)alloc((size_t)BB * T * H * 4);     // 19.7 MB
    float* res_h = (float*)alloc((size_t)BB * SLOTS * H * 4); // 4.9 MB
    float* res_c = (float*)alloc((size_t)BB * SLOTS * H * 4); // 4.9 MB
    float* Wt    = (float*)alloc((size_t)1500 * KP * 4);      // 3.65 MB
    float* bpr   = (float*)alloc(1500 * 4);
    int* sl      = (int*)alloc((size_t)NT * BB * 4);
    int* sr      = (int*)alloc((size_t)NT * BB * 4);
    int* sd      = (int*)alloc((size_t)NT * BB * 4);
    int* ev_t    = (int*)alloc(256 * 4);
    int* ne      = (int*)alloc(4);
    int* root    = (int*)alloc(BB * 4);
    int* done    = (int*)alloc(RG * 256 * 4);
    (void)ws_size; (void)in_sizes; (void)n_in; (void)out_size;

    hipMemsetAsync(done, 0, RG * 256 * 4, stream);
    prep_kernel<<<(1500 * KP + 255) / 256, 256, 0, stream>>>(Wr, br, Wt, bpr);
    sched_kernel<<<1, BB, 0, stream>>>(trans, sl, sr, sd, root);
    events_kernel<<<1, 256, 0, stream>>>(trans, ev_t, ne);
    prologue_kernel<<<(BB * T) / 32, 320, 0, stream>>>(tokens, embed, Wp, bp, Wg, bg, hbuf, cbuf);

    ScanArgs sa { sl, sr, sd, ev_t, ne, hbuf, cbuf, res_h, res_c, Wt, bpr, done };
    void* args[] = { &sa };
    hipLaunchCooperativeKernel((const void*)scan_kernel, dim3(RG * CB), dim3(SCAN_THREADS),
                               args, 0, stream);

    epilogue_kernel<<<BB, 64, 0, stream>>>(root, hbuf, res_h, Wo, bo, out);
}

// Round 7
// 3288.961 us; speedup vs baseline: 3.7552x; 1.1923x over previous
//
#include <hip/hip_runtime.h>

#define VOCAB 100000
#define E 300
#define H 300
#define T 128
#define BB 128
#define NT 255   // 2T-1
#define PAD 1
#define NOUT 5

// scan configuration
#define RG 8          // row groups (16 rows each)
#define RPB 16        // rows per block
#define CB 30         // col blocks (10 h-dims each)
#define DPB 10        // h dims per block
#define COLS 50       // gate cols per block (5*DPB)
#define KP 608        // padded K (600 -> 608)
#define KC16 16       // k chunks per column (matvec)
#define KT16 38       // k per chunk (608/16); 38%32=6 -> 16 distinct even bank residues
#define SCAN_THREADS 320
#define CU_THREADS 160   // 16 rows x 10 dims
#define SLOTS 32
#define EMAX 256

__device__ __forceinline__ float sigmoidf_(float x) { return 1.0f / (1.0f + expf(-x)); }

// ---------------------------------------------------------------------------
// Prep: transpose W_reduce to col-major, reorder cols by (cb, gate, jj), pad K.
// Wt[col'][k], col' = cb*50 + g*10 + jj  <->  orig col j = g*300 + cb*10 + jj
// ---------------------------------------------------------------------------
__global__ void prep_kernel(const float* __restrict__ Wr, const float* __restrict__ br,
                            float* __restrict__ Wt, float* __restrict__ bpr) {
    int idx = blockIdx.x * 256 + threadIdx.x;
    int total = 1500 * KP;
    if (idx < total) {
        int col = idx / KP, k = idx % KP;
        int cb = col / COLS, rr = col % COLS;
        int g = rr / DPB, jj = rr % DPB;
        int jo = g * 300 + cb * DPB + jj;
        Wt[idx] = (k < 600) ? Wr[k * 1500 + jo] : 0.0f;
        if (k == 0) bpr[col] = br[jo];
    }
}

// ---------------------------------------------------------------------------
// Schedule: per-row stack-machine replay (tags: -1 zero, [0,128) leaf, >=1000 rid)
// ---------------------------------------------------------------------------
__global__ void sched_kernel(const int* __restrict__ trans,
                             int* __restrict__ sl, int* __restrict__ sr, int* __restrict__ sd,
                             int* __restrict__ root_tag) {
    __shared__ int stk[64][BB];
    int row = threadIdx.x;               // 128 threads
    for (int d = 0; d < 64; ++d) stk[d][row] = -1;
    int sp = 0, bp = T - 1, rid = 0;
    for (int t = 0; t < NT; ++t) {
        int tr = trans[t * BB + row];
        int lt = -1, rt = -1, ds = -1;
        if (tr == 0) {
            int leaf = bp > 0 ? bp : 0;
            if (sp >= 0 && sp < 64) stk[sp][row] = leaf;
            sp += 1; bp -= 1;
        } else {
            int ip = sp - 2 > 0 ? sp - 2 : 0; if (ip > 63) ip = 63;
            int rp = sp - 1 > 0 ? sp - 1 : 0; if (rp > 63) rp = 63;
            lt = stk[ip][row];
            rt = stk[rp][row];
            ds = rid;
            stk[ip][row] = 1000 + rid;
            rid += 1; sp -= 1;
        }
        sl[t * BB + row] = lt; sr[t * BB + row] = rt; sd[t * BB + row] = ds;
    }
    int rp = sp - 1 > 0 ? sp - 1 : 0; if (rp > 63) rp = 63;
    root_tag[row] = stk[rp][row];
}

// ---------------------------------------------------------------------------
// Events: steps where any row reduces
// ---------------------------------------------------------------------------
__global__ void events_kernel(const int* __restrict__ trans,
                              int* __restrict__ ev_t, int* __restrict__ ne) {
    __shared__ int anyf[NT];
    int t = threadIdx.x;
    if (t < NT) {
        const int4* p = (const int4*)(trans + t * BB);
        int o = 0;
        for (int i = 0; i < BB / 4; ++i) { int4 v = p[i]; o |= v.x | v.y | v.z | v.w; }
        anyf[t] = (o != 0) ? 1 : 0;
    }
    __syncthreads();
    if (t == 0) {
        int n = 0;
        for (int i = 0; i < NT; ++i) if (anyf[i]) ev_t[n++] = i;
        *ne = n;
    }
}

// ---------------------------------------------------------------------------
// Prologue: h_buf/c_buf. float4 LDS broadcast reads -> VALU-bound.
// ---------------------------------------------------------------------------
__global__ __launch_bounds__(320) void prologue_kernel(
    const int* __restrict__ tokens, const float* __restrict__ embed,
    const float* __restrict__ Wp, const float* __restrict__ bp_,
    const float* __restrict__ Wg, const float* __restrict__ bg_,
    float* __restrict__ hbuf, float* __restrict__ cbuf) {
    __shared__ __align__(16) float As[32][304];
    int m0 = blockIdx.x * 32;
    int tid = threadIdx.x;
    for (int idx = tid; idx < 32 * 300; idx += 320) {
        int r = idx / 300, c = idx % 300;
        int tok = tokens[m0 + r];
        As[r][c] = (tok == PAD) ? 0.0f : embed[(size_t)tok * 300 + c];
    }
    __syncthreads();
    int n = tid;
    if (n < 300) {
        float accP[32], accG[32];
        #pragma unroll
        for (int m = 0; m < 32; ++m) { accP[m] = 0.f; accG[m] = 0.f; }
        #pragma unroll 1
        for (int k4 = 0; k4 < 75; ++k4) {
            int k = k4 * 4;
            float wp0 = Wp[(k + 0) * 300 + n], wp1 = Wp[(k + 1) * 300 + n];
            float wp2 = Wp[(k + 2) * 300 + n], wp3 = Wp[(k + 3) * 300 + n];
            float wg0 = Wg[(k + 0) * 300 + n], wg1 = Wg[(k + 1) * 300 + n];
            float wg2 = Wg[(k + 2) * 300 + n], wg3 = Wg[(k + 3) * 300 + n];
            #pragma unroll
            for (int m = 0; m < 32; ++m) {
                float4 av = *(const float4*)(&As[m][k]);
                accP[m] += av.x * wp0 + av.y * wp1 + av.z * wp2 + av.w * wp3;
                accG[m] += av.x * wg0 + av.y * wg1 + av.z * wg2 + av.w * wg3;
            }
        }
        float bpv = bp_[n], bgv = bg_[n];
        #pragma unroll 1
        for (int m = 0; m < 32; ++m) {
            float c = accP[m] + bpv;
            float g = accG[m] + bgv;
            float h = tanhf(c) * sigmoidf_(g);
            hbuf[(size_t)(m0 + m) * 300 + n] = h;
            cbuf[(size_t)(m0 + m) * 300 + n] = c;
        }
    }
}

// ---------------------------------------------------------------------------
// Scan: persistent kernel, 240 blocks = 8 row-groups x 30 col-blocks.
// rg = bid & 7  -> all 30 blocks of a row-group land on one XCD (round-robin
// dispatch heuristic; perf-only). Cross-block data (res_h) and flags go via
// MALL: wide sc0 sc1 loads (inline asm, coalesced) + relaxed atomic stores.
// Flags: one word per (event, rg, cb); consumer ballots 30 lanes. No RMW.
// ---------------------------------------------------------------------------
struct ScanArgs {
    const int* sl; const int* sr; const int* sd;
    const int* ev_t; const int* ne;
    const float* hbuf; const float* cbuf;
    float* res_h; float* res_c;
    const float* Wt; const float* bpr;
    int* done;
};

__global__ __launch_bounds__(SCAN_THREADS) void scan_kernel(ScanArgs a) {
    __shared__ __align__(16) float xs[RPB * KP];     // 38.9 KB  [h_l | h_r | pad] per row
    __shared__ float sums[COLS][17];                 // padded: conflict-free cell reads
    __shared__ int evl[EMAX];
    __shared__ short sle[EMAX][RPB], sre[EMAX][RPB], sde[EMAX][RPB];
    const int tid = threadIdx.x;
    const int bid = blockIdx.x;
    const int rg = bid & 7;            // XCD-local row-group
    const int cb = bid >> 3;
    const int row0 = rg * RPB;
    const int NEv = *a.ne;

    // ---- one-time: preload event times + per-event tags for this row-group
    if (tid < EMAX) evl[tid] = (tid < NEv) ? a.ev_t[tid] : 0;
    __syncthreads();
    for (int idx = tid; idx < NEv * RPB; idx += SCAN_THREADS) {
        int e = idx / RPB, r = idx - e * RPB;
        int t = evl[e];
        sle[e][r] = (short)a.sl[t * BB + row0 + r];
        sre[e][r] = (short)a.sr[t * BB + row0 + r];
        sde[e][r] = (short)a.sd[t * BB + row0 + r];
    }
    __syncthreads();

    for (int e = 0; e < NEv; ++e) {
        // ---- phase A: stage leaves/zeros (everything not depending on prev event)
        #pragma unroll
        for (int i = 0; i < 8; ++i) {
            int it = tid + i * SCAN_THREADS;
            if (it < RPB * (KP / 4)) {
                int r = it / (KP / 4), q = it - r * (KP / 4);
                int k = q * 4;
                int tag = (k < 300) ? (int)sle[e][r] : ((k < 600) ? (int)sre[e][r] : -1);
                if (tag < 1000) {
                    float4 v = make_float4(0.f, 0.f, 0.f, 0.f);
                    if (tag >= 0) {
                        int kk = (k < 300) ? k : k - 300;
                        v = *(const float4*)(a.hbuf + ((size_t)(row0 + r) * T + tag) * H + kk);
                    }
                    *(float4*)&xs[r * KP + k] = v;
                }
            }
        }

        // ---- wait for previous event (30-lane ballot poll, no sleep, no RMW)
        if (e > 0 && tid < 64) {
            const int* fp = a.done + (((e - 1) << 3) + rg) * 32 + tid;
            int guard = 0;
            bool ok;
            do {
                int v = (tid < CB) ? __hip_atomic_load(fp, __ATOMIC_RELAXED,
                                                       __HIP_MEMORY_SCOPE_AGENT) : 0;
                ok = (tid < CB) ? (v == e) : true;
            } while (!__all(ok) && ++guard < (1 << 24));
        }
        __syncthreads();

        // ---- phase B: chain operands from res_h via coalesced sc0sc1 dwordx4
        {
            float4 v0, v1, v2, v3, v4, v5, v6, v7;
            int w0 = -1, w1 = -1, w2 = -1, w3 = -1, w4 = -1, w5 = -1, w6 = -1, w7 = -1;
            #define PHB_SLOT(i) { \
                int it = tid + (i) * SCAN_THREADS; \
                if (it < 2400) { \
                    int side = (it >= 1200); int rem = it - (side ? 1200 : 0); \
                    int r = rem / 75, q = rem - r * 75; \
                    int tag = side ? (int)sre[e][r] : (int)sle[e][r]; \
                    if (tag >= 1000) { \
                        const float* s_ = a.res_h + \
                            ((size_t)(row0 + r) * SLOTS + ((tag - 1000) & (SLOTS - 1))) * H + q * 4; \
                        asm volatile("global_load_dwordx4 %0, %1, off sc0 sc1" \
                                     : "=v"(v##i) : "v"(s_)); \
                        w##i = r * KP + (side ? 300 : 0) + q * 4; \
                    } \
                } }
            PHB_SLOT(0) PHB_SLOT(1) PHB_SLOT(2) PHB_SLOT(3)
            PHB_SLOT(4) PHB_SLOT(5) PHB_SLOT(6) PHB_SLOT(7)
            #undef PHB_SLOT
            asm volatile("s_waitcnt vmcnt(0)" ::: "memory");
            if (w0 >= 0) *(float4*)&xs[w0] = v0;
            if (w1 >= 0) *(float4*)&xs[w1] = v1;
            if (w2 >= 0) *(float4*)&xs[w2] = v2;
            if (w3 >= 0) *(float4*)&xs[w3] = v3;
            if (w4 >= 0) *(float4*)&xs[w4] = v4;
            if (w5 >= 0) *(float4*)&xs[w5] = v5;
            if (w6 >= 0) *(float4*)&xs[w6] = v6;
            if (w7 >= 0) *(float4*)&xs[w7] = v7;
        }
        __syncthreads();

        // ---- matvec: all 320 threads = (10 col-groups of 5) x (2 row-halves) x (16 kc)
        {
            int kc = tid & 15;
            int rh = (tid >> 4) & 1;
            int jg = tid >> 5;                  // 0..9
            int r0 = rh * 8;
            const float* wb = a.Wt + (size_t)(cb * COLS + jg * 5) * KP + kc * KT16;
            const float* xb = xs + kc * KT16;
            float acc[5][8];
            #pragma unroll
            for (int cc = 0; cc < 5; ++cc)
                #pragma unroll
                for (int rr = 0; rr < 8; ++rr) acc[cc][rr] = 0.f;
            #pragma unroll 1
            for (int s = 0; s < KT16 / 2; ++s) {
                float2 w0 = *(const float2*)(wb + 0 * KP + s * 2);
                float2 w1 = *(const float2*)(wb + 1 * KP + s * 2);
                float2 w2 = *(const float2*)(wb + 2 * KP + s * 2);
                float2 w3 = *(const float2*)(wb + 3 * KP + s * 2);
                float2 w4 = *(const float2*)(wb + 4 * KP + s * 2);
                #pragma unroll
                for (int rr = 0; rr < 8; ++rr) {
                    float2 x = *(const float2*)(xb + (r0 + rr) * KP + s * 2);
                    acc[0][rr] += w0.x * x.x + w0.y * x.y;
                    acc[1][rr] += w1.x * x.x + w1.y * x.y;
                    acc[2][rr] += w2.x * x.x + w2.y * x.y;
                    acc[3][rr] += w3.x * x.x + w3.y * x.y;
                    acc[4][rr] += w4.x * x.x + w4.y * x.y;
                }
            }
            #pragma unroll
            for (int d = 1; d < 16; d <<= 1)
                #pragma unroll
                for (int cc = 0; cc < 5; ++cc)
                    #pragma unroll
                    for (int rr = 0; rr < 8; ++rr)
                        acc[cc][rr] += __shfl_xor(acc[cc][rr], d, 64);
            if (kc == 0) {
                #pragma unroll
                for (int cc = 0; cc < 5; ++cc) {
                    float bb = a.bpr[cb * COLS + jg * 5 + cc];
                    #pragma unroll
                    for (int rr = 0; rr < 8; ++rr)
                        sums[jg * 5 + cc][r0 + rr] = acc[cc][rr] + bb;
                }
            }
        }
        __syncthreads();

        // ---- cell update: 16 rows x 10 dims; res_c block-private (cached),
        //      res_h published via coherence-point (sc0sc1) stores
        if (tid < CU_THREADS) {
            int r = tid & 15, jj = tid >> 4;
            int ds = (int)sde[e][r];
            if (ds >= 0) {
                int dim = cb * DPB + jj;
                float iv = sums[jj][r];
                float fl = sums[DPB + jj][r];
                float fr = sums[2 * DPB + jj][r];
                float gv = sums[3 * DPB + jj][r];
                float ov = sums[4 * DPB + jj][r];
                int lt = (int)sle[e][r], rt = (int)sre[e][r];
                float cl = 0.f, cr = 0.f;
                if (lt >= 0) cl = (lt < 1000)
                    ? a.cbuf[((size_t)(row0 + r) * T + lt) * H + dim]
                    : a.res_c[((size_t)(row0 + r) * SLOTS + ((lt - 1000) & (SLOTS - 1))) * H + dim];
                if (rt >= 0) cr = (rt < 1000)
                    ? a.cbuf[((size_t)(row0 + r) * T + rt) * H + dim]
                    : a.res_c[((size_t)(row0 + r) * SLOTS + ((rt - 1000) & (SLOTS - 1))) * H + dim];
                float c = sigmoidf_(iv) * tanhf(gv) + sigmoidf_(fl) * cl + sigmoidf_(fr) * cr;
                float h = sigmoidf_(ov) * tanhf(c);
                size_t ro = ((size_t)(row0 + r) * SLOTS + (ds & (SLOTS - 1))) * H + dim;
                a.res_c[ro] = c;                                  // block-private, cached
                __hip_atomic_store(&a.res_h[ro], h, __ATOMIC_RELAXED,
                                   __HIP_MEMORY_SCOPE_AGENT);     // through to MALL
            }
        }
        // drain own stores, then publish this block's per-cb flag (no RMW)
        asm volatile("s_waitcnt vmcnt(0)" ::: "memory");
        __syncthreads();
        if (tid == 0)
            __hip_atomic_store(&a.done[((e << 3) + rg) * 32 + cb], e + 1,
                               __ATOMIC_RELAXED, __HIP_MEMORY_SCOPE_AGENT);
    }
}

// ---------------------------------------------------------------------------
// Epilogue: out = root_h @ W_out + b_out
// ---------------------------------------------------------------------------
__global__ void epilogue_kernel(const int* __restrict__ root_tag,
                                const float* __restrict__ hbuf, const float* __restrict__ res_h,
                                const float* __restrict__ Wo, const float* __restrict__ bo,
                                float* __restrict__ out) {
    int row = blockIdx.x;
    int lane = threadIdx.x;  // 64
    int tag = root_tag[row];
    const float* h = nullptr;
    if (tag >= 0)
        h = (tag < 1000) ? hbuf + ((size_t)row * T + tag) * H
                         : res_h + ((size_t)row * SLOTS + ((tag - 1000) & (SLOTS - 1))) * H;
    float acc[NOUT] = {0, 0, 0, 0, 0};
    for (int k = lane; k < H; k += 64) {
        float hv = h ? h[k] : 0.f;
        #pragma unroll
        for (int g = 0; g < NOUT; ++g) acc[g] += hv * Wo[k * NOUT + g];
    }
    #pragma unroll
    for (int d = 1; d < 64; d <<= 1) {
        #pragma unroll
        for (int g = 0; g < NOUT; ++g) acc[g] += __shfl_xor(acc[g], d, 64);
    }
    if (lane == 0) {
        #pragma unroll
        for (int g = 0; g < NOUT; ++g) out[row * NOUT + g] = acc[g] + bo[g];
    }
}

// ---------------------------------------------------------------------------
extern "C" void kernel_launch(void* const* d_in, const int* in_sizes, int n_in,
                              void* d_out, int out_size, void* d_ws, size_t ws_size,
                              hipStream_t stream) {
    const int*   tokens = (const int*)d_in[0];
    const int*   trans  = (const int*)d_in[1];
    const float* embed  = (const float*)d_in[2];
    const float* Wp     = (const float*)d_in[3];
    const float* bp     = (const float*)d_in[4];
    const float* Wg     = (const float*)d_in[5];
    const float* bg     = (const float*)d_in[6];
    const float* Wr     = (const float*)d_in[7];
    const float* br     = (const float*)d_in[8];
    const float* Wo     = (const float*)d_in[9];
    const float* bo     = (const float*)d_in[10];
    float* out = (float*)d_out;

    char* ws = (char*)d_ws;
    size_t o = 0;
    auto alloc = [&](size_t bytes) {
        char* p = ws + o;
        o = (o + bytes + 255) & ~(size_t)255;
        return p;
    };
    float* hbuf  = (float*)alloc((size_t)BB * T * H * 4);     // 19.7 MB
    float* cbuf  = (float*)alloc((size_t)BB * T * H * 4);     // 19.7 MB
    float* res_h = (float*)alloc((size_t)BB * SLOTS * H * 4); // 4.9 MB
    float* res_c = (float*)alloc((size_t)BB * SLOTS * H * 4); // 4.9 MB
    float* Wt    = (float*)alloc((size_t)1500 * KP * 4);      // 3.65 MB
    float* bpr   = (float*)alloc(1500 * 4);
    int* sl      = (int*)alloc((size_t)NT * BB * 4);
    int* sr      = (int*)alloc((size_t)NT * BB * 4);
    int* sd      = (int*)alloc((size_t)NT * BB * 4);
    int* ev_t    = (int*)alloc(EMAX * 4);
    int* ne      = (int*)alloc(4);
    int* root    = (int*)alloc(BB * 4);
    int* done    = (int*)alloc((size_t)EMAX * 8 * 32 * 4);    // 256 KB flag array
    (void)ws_size; (void)in_sizes; (void)n_in; (void)out_size;

    hipMemsetAsync(done, 0, (size_t)EMAX * 8 * 32 * 4, stream);
    prep_kernel<<<(1500 * KP + 255) / 256, 256, 0, stream>>>(Wr, br, Wt, bpr);
    sched_kernel<<<1, BB, 0, stream>>>(trans, sl, sr, sd, root);
    events_kernel<<<1, 256, 0, stream>>>(trans, ev_t, ne);
    prologue_kernel<<<(BB * T) / 32, 320, 0, stream>>>(tokens, embed, Wp, bp, Wg, bg, hbuf, cbuf);

    ScanArgs sa { sl, sr, sd, ev_t, ne, hbuf, cbuf, res_h, res_c, Wt, bpr, done };
    void* args[] = { &sa };
    hipLaunchCooperativeKernel((const void*)scan_kernel, dim3(RG * CB), dim3(SCAN_THREADS),
                               args, 0, stream);

    epilogue_kernel<<<BB, 64, 0, stream>>>(root, hbuf, res_h, Wo, bo, out);
}